// Round 18
// baseline (222.938 us; speedup 1.0000x reference)
//
#include <hip/hip_runtime.h>

typedef __bf16 bf16x8 __attribute__((ext_vector_type(8)));
typedef __bf16 bf16x4 __attribute__((ext_vector_type(4)));
typedef float f32x4 __attribute__((ext_vector_type(4)));
typedef unsigned short u16;

#if __has_builtin(__builtin_amdgcn_exp2f)
#define EXP2(x) __builtin_amdgcn_exp2f(x)
#else
#define EXP2(x) exp2f(x)
#endif

__device__ __forceinline__ float bf2f(u16 u){
    union { unsigned int i; float f; } x; x.i = ((unsigned int)u) << 16; return x.f;
}
// native f32->bf16 (compiler emits v_cvt_pk_bf16_f32 for pairs)
__device__ __forceinline__ u16 bfbits(float f){
    __bf16 h = (__bf16)f;
    union { __bf16 b; u16 u; } x; x.b = h; return x.u;
}
__device__ __forceinline__ int4 cvt8(const float4 a, const float4 b){
    union { __bf16 h[8]; int4 v; } u;
    u.h[0] = (__bf16)a.x; u.h[1] = (__bf16)a.y; u.h[2] = (__bf16)a.z; u.h[3] = (__bf16)a.w;
    u.h[4] = (__bf16)b.x; u.h[5] = (__bf16)b.y; u.h[6] = (__bf16)b.z; u.h[7] = (__bf16)b.w;
    return u.v;
}
// async global->LDS, 16B per lane; dest is wave-uniform base (HW adds lane*16)
__device__ __forceinline__ void gload_lds16(const void* g, void* l){
    __builtin_amdgcn_global_load_lds(
        (const __attribute__((address_space(1))) unsigned int*)g,
        (__attribute__((address_space(3))) unsigned int*)l, 16, 0, 0);
}

// ---------------------------------------------------------------------------
// Transpose 4 x [1024][1024] f32 weights -> bf16 Wt [N][K]
// ---------------------------------------------------------------------------
__global__ __launch_bounds__(256) void transpose4(
    const float* __restrict__ w0, const float* __restrict__ w1,
    const float* __restrict__ w2, const float* __restrict__ w3,
    u16* __restrict__ out)
{
    __shared__ float tile[32][33];
    int mat = blockIdx.z;
    const float* in = (mat == 0) ? w0 : (mat == 1) ? w1 : (mat == 2) ? w2 : w3;
    u16* o = out + (size_t)mat * 1048576;
    int bx = blockIdx.x * 32, by = blockIdx.y * 32;
    int tx = threadIdx.x & 31, ty = threadIdx.x >> 5; // 32 x 8
    #pragma unroll
    for (int i = 0; i < 32; i += 8)
        tile[ty + i][tx] = in[(size_t)(by + ty + i) * 1024 + bx + tx];
    __syncthreads();
    #pragma unroll
    for (int i = 0; i < 32; i += 8)
        o[(size_t)(bx + ty + i) * 1024 + by + tx] = bfbits(tile[tx][ty + i]);
}

// ---------------------------------------------------------------------------
// Fused Q/K/V projection GEMM v3: BK=64 (32 MFMA per barrier, halves the
// barrier/drain count that m233-style analysis says dominates 2-phase GEMMs).
// 128B LDS rows with (row&7)<<4 XOR swizzle (attn-proven; 2-way = free).
// gload_lds B (pre-swizzled source), reg-staged f32->bf16 A interleaved with
// the two MFMA sub-steps (16 live staging regs). Ct-LDS coalesced epilogue.
// seg 0/1 store [b][h][q][d] (seg0 scaled); seg 2 stores [b][h][d][q].
// ---------------------------------------------------------------------------
__global__ __launch_bounds__(256) void gemm_qkv(
    const float* __restrict__ Aq, const float* __restrict__ Ak,
    const float* __restrict__ Avv, const u16* __restrict__ Wt3,
    const float* __restrict__ bq, const float* __restrict__ bk,
    const float* __restrict__ bv,
    u16* __restrict__ Qp, u16* __restrict__ Kp, u16* __restrict__ Vtd,
    float qscale)
{
    constexpr int K = 1024;
    __shared__ alignas(16) u16 smem[32768];      // 64 KB: As 2x16K | Bs 2x16K
    char* const AB = (char*)smem;
    auto Abase = [&](int buf){ return AB + buf * 16384; };
    auto Bbase = [&](int buf){ return AB + 32768 + buf * 16384; };

    const int tid = threadIdx.x;
    const int lane = tid & 63, wid = tid >> 6;
    const int wm = wid >> 1, wn = wid & 1;

    const int wg = blockIdx.x;                   // 0..1535
    const int seg = wg >> 9;                     // 0..2
    const int w = wg & 511;
    const int xcd = w & 7, rest = w >> 3;
    const int ntile = rest & 7, mhi = rest >> 3;
    const int m0 = (mhi * 8 + xcd) * 128;
    const int n0 = ntile * 128;

    const float* A = (seg == 0) ? Aq : (seg == 1) ? Ak : Avv;
    const u16* Bt = Wt3 + (size_t)seg * 1048576;
    const float* bias = (seg == 0) ? bq : (seg == 1) ? bk : bv;
    const float scale = (seg == 0) ? qscale : 1.0f;
    u16* Cv = (seg == 0) ? Qp : (seg == 1) ? Kp : Vtd;
    const bool vmode = (seg == 2);

    const int r0 = tid >> 2;            // A row 0..63 (and +64)
    const int cq = tid & 3;             // col-quarter: 16 f32 each
    const int fr = lane & 15;
    const int fkB = (lane >> 4) * 16;   // fragment byte col within 64B half

    const float* Af0 = A + (size_t)(m0 + r0) * K + cq * 16;
    const float* Af1 = Af0 + (size_t)64 * K;

    // B stage: 4 insts/wave, 8 rows (1 KB) each; source chunk pre-XORed
    auto stageB = [&](int buf, int tcol) {
        #pragma unroll
        for (int i = 0; i < 4; i++) {
            int rt = wid * 32 + i * 8;
            int r = rt + (lane >> 3);
            gload_lds16(Bt + (size_t)(n0 + r) * K + tcol + ((lane & 7) ^ (r & 7)) * 8,
                        Bbase(buf) + rt * 128);
        }
    };
    // A write: one row's 16 bf16 (two swizzled 16B chunks)
    auto writeA = [&](int buf, int row, int4 lo, int4 hi) {
        int sw = (row & 7) << 4;
        *(int4*)(Abase(buf) + row * 128 + ((cq * 32) ^ sw)) = lo;
        *(int4*)(Abase(buf) + row * 128 + ((cq * 32 + 16) ^ sw)) = hi;
    };

    // prologue: stage K-tile 0
    stageB(0, 0);
    {
        const float4* p0 = (const float4*)Af0;
        writeA(0, r0, cvt8(p0[0], p0[1]), cvt8(p0[2], p0[3]));
        const float4* p1 = (const float4*)Af1;
        writeA(0, r0 + 64, cvt8(p1[0], p1[1]), cvt8(p1[2], p1[3]));
    }
    __syncthreads();

    f32x4 acc[4][4] = {};
    constexpr int NT = K / 64;          // 16 K-tiles
    for (int t = 0; t < NT; ++t) {
        const int cur = t & 1, nxt = cur ^ 1;
        float4 h0, h1, h2, h3;
        if (t + 1 < NT) {
            stageB(nxt, (t + 1) * 64);
            const float4* p = (const float4*)(Af0 + (t + 1) * 64);
            h0 = p[0]; h1 = p[1]; h2 = p[2]; h3 = p[3];
        }
        // sub-step 0 (K 0..31 of tile)
        {
            bf16x8 af[4], bfr[4];
            #pragma unroll
            for (int i = 0; i < 4; i++) {
                int ra = wm * 64 + i * 16 + fr;
                int rb = wn * 64 + i * 16 + fr;
                af[i]  = *(const bf16x8*)(Abase(cur) + ra * 128 + (fkB ^ ((ra & 7) << 4)));
                bfr[i] = *(const bf16x8*)(Bbase(cur) + rb * 128 + (fkB ^ ((rb & 7) << 4)));
            }
            #pragma unroll
            for (int mi = 0; mi < 4; mi++)
                #pragma unroll
                for (int ni = 0; ni < 4; ni++)
                    acc[mi][ni] = __builtin_amdgcn_mfma_f32_16x16x32_bf16(
                        af[mi], bfr[ni], acc[mi][ni], 0, 0, 0);
        }
        if (t + 1 < NT) {
            writeA(nxt, r0, cvt8(h0, h1), cvt8(h2, h3));
            const float4* p = (const float4*)(Af1 + (t + 1) * 64);
            h0 = p[0]; h1 = p[1]; h2 = p[2]; h3 = p[3];
        }
        // sub-step 1 (K 32..63 of tile)
        {
            bf16x8 af[4], bfr[4];
            #pragma unroll
            for (int i = 0; i < 4; i++) {
                int ra = wm * 64 + i * 16 + fr;
                int rb = wn * 64 + i * 16 + fr;
                af[i]  = *(const bf16x8*)(Abase(cur) + ra * 128 + ((64 + fkB) ^ ((ra & 7) << 4)));
                bfr[i] = *(const bf16x8*)(Bbase(cur) + rb * 128 + ((64 + fkB) ^ ((rb & 7) << 4)));
            }
            #pragma unroll
            for (int mi = 0; mi < 4; mi++)
                #pragma unroll
                for (int ni = 0; ni < 4; ni++)
                    acc[mi][ni] = __builtin_amdgcn_mfma_f32_16x16x32_bf16(
                        af[mi], bfr[ni], acc[mi][ni], 0, 0, 0);
        }
        if (t + 1 < NT) {
            writeA(nxt, r0 + 64, cvt8(h0, h1), cvt8(h2, h3));
        }
        __syncthreads();
    }

    // epilogue: acc -> Ct (bf16, swizzled, aliases As) -> coalesced stores
    char* const CtB = AB;
    #pragma unroll
    for (int ni = 0; ni < 4; ni++) {
        int nn = wn * 64 + ni * 16 + fr;
        float bcol = bias[n0 + nn];
        #pragma unroll
        for (int mi = 0; mi < 4; mi++) {
            #pragma unroll
            for (int r = 0; r < 4; r++) {
                int mm = wm * 64 + mi * 16 + (lane >> 4) * 4 + r;
                float val = (acc[mi][ni][r] + bcol) * scale;
                int row  = vmode ? nn : mm;
                int colb = (vmode ? mm : nn) * 2;
                *(u16*)(CtB + row * 256 +
                        ((colb & 15) | ((((colb >> 4)) ^ (row & 7)) << 4))) = bfbits(val);
            }
        }
    }
    __syncthreads();
    #pragma unroll
    for (int p = 0; p < 8; p++) {
        int idx = p * 256 + tid;
        int row = idx >> 4, ck = idx & 15;
        int4 val = *(const int4*)(CtB + row * 256 + ((ck ^ (row & 7)) << 4));
        if (vmode) {
            int n = n0 + row, m = m0 + ck * 8;
            int h = n >> 6, d = n & 63, bb = m >> 11, q = m & 2047;
            *(int4*)&Cv[(size_t)(bb * 16 + h) * 131072 + (size_t)d * 2048 + q] = val;
        } else {
            int m = m0 + row, n = n0 + ck * 8;
            int h = n >> 6, d = n & 63, bb = m >> 11, q = m & 2047;
            *(int4*)&Cv[(size_t)(bb * 16 + h) * 131072 + (size_t)q * 64 + d] = val;
        }
    }
}

// ---------------------------------------------------------------------------
// O-projection GEMM (bf16 A via gload_lds, f32 residual, bf16 row-major out)
// (row>>1)&3 swizzle (conflict-free, R17-verified). Unchanged.
// ---------------------------------------------------------------------------
__global__ __launch_bounds__(256) void gemm_o(
    const u16* __restrict__ Ah, const u16* __restrict__ Bt,
    const float* __restrict__ bias, const float* __restrict__ resid,
    u16* __restrict__ Cv)
{
    constexpr int K = 1024;
    __shared__ alignas(16) u16 smem[16384];
    char* const AB = (char*)smem;
    auto Abase = [&](int buf){ return AB + buf * 8192; };
    auto Bbase = [&](int buf){ return AB + 16384 + buf * 8192; };

    const int tid = threadIdx.x;
    const int lane = tid & 63, wid = tid >> 6;
    const int wm = wid >> 1, wn = wid & 1;

    const int wg = blockIdx.x;                   // 0..511
    const int xcd = wg & 7, rest = wg >> 3;
    const int ntile = rest & 7, mhi = rest >> 3;
    const int m0 = (mhi * 8 + xcd) * 128;
    const int n0 = ntile * 128;

    const int fr = lane & 15;
    const int fkB = (lane >> 4) * 16;

    const int srow = lane >> 2;
    auto stageB = [&](int buf, int tcol) {
        #pragma unroll
        for (int i = 0; i < 2; i++) {
            int rt = wid * 32 + i * 16;
            int r = rt + srow;
            gload_lds16(Bt + (size_t)(n0 + r) * K + tcol + ((lane & 3) ^ ((r >> 1) & 3)) * 8,
                        Bbase(buf) + rt * 64);
        }
    };
    auto stageA = [&](int buf, int tcol) {
        #pragma unroll
        for (int i = 0; i < 2; i++) {
            int rt = wid * 32 + i * 16;
            int r = rt + srow;
            gload_lds16(Ah + (size_t)(m0 + r) * K + tcol + ((lane & 3) ^ ((r >> 1) & 3)) * 8,
                        Abase(buf) + rt * 64);
        }
    };

    stageB(0, 0);
    stageA(0, 0);
    __syncthreads();

    f32x4 acc[4][4] = {};
    constexpr int NT = K / 32;
    for (int t = 0; t < NT; ++t) {
        const int cur = t & 1, nxt = cur ^ 1;
        if (t + 1 < NT) {
            stageB(nxt, (t + 1) * 32);
            stageA(nxt, (t + 1) * 32);
        }
        bf16x8 af[4], bfr[4];
        #pragma unroll
        for (int i = 0; i < 4; i++) {
            int ra = wm * 64 + i * 16 + fr;
            int rb = wn * 64 + i * 16 + fr;
            af[i]  = *(const bf16x8*)(Abase(cur) + ra * 64 + (fkB ^ (((ra >> 1) & 3) << 4)));
            bfr[i] = *(const bf16x8*)(Bbase(cur) + rb * 64 + (fkB ^ (((rb >> 1) & 3) << 4)));
        }
        #pragma unroll
        for (int mi = 0; mi < 4; mi++)
            #pragma unroll
            for (int ni = 0; ni < 4; ni++)
                acc[mi][ni] = __builtin_amdgcn_mfma_f32_16x16x32_bf16(
                    af[mi], bfr[ni], acc[mi][ni], 0, 0, 0);
        __syncthreads();
    }

    char* const CtB = AB;
    #pragma unroll
    for (int ni = 0; ni < 4; ni++) {
        int nn = wn * 64 + ni * 16 + fr;
        float bcol = bias[n0 + nn];
        #pragma unroll
        for (int mi = 0; mi < 4; mi++) {
            #pragma unroll
            for (int r = 0; r < 4; r++) {
                int mm = wm * 64 + mi * 16 + (lane >> 4) * 4 + r;
                float val = acc[mi][ni][r] + bcol + resid[(size_t)(m0 + mm) * 1024 + n0 + nn];
                int colb = nn * 2;
                *(u16*)(CtB + mm * 256 +
                        ((colb & 15) | ((((colb >> 4)) ^ (mm & 7)) << 4))) = bfbits(val);
            }
        }
    }
    __syncthreads();
    #pragma unroll
    for (int p = 0; p < 8; p++) {
        int idx = p * 256 + tid;
        int row = idx >> 4, ck = idx & 15;
        int4 val = *(const int4*)(CtB + row * 256 + ((ck ^ (row & 7)) << 4));
        *(int4*)&Cv[(size_t)(m0 + row) * 1024 + n0 + ck * 8] = val;
    }
}

// ---------------------------------------------------------------------------
// Flash attention v7: swapped QK^T with fused per-kb exp2, softmax-lite,
// gload_lds K/V staging, XCD-bijective swizzle, 4 blocks/CU. (unchanged)
// ---------------------------------------------------------------------------
__global__ __launch_bounds__(256, 4) void attn_k(
    const u16* __restrict__ Qp, const u16* __restrict__ Kp,
    const u16* __restrict__ Vt, const int* __restrict__ mask,
    u16* __restrict__ O)
{
    __shared__ alignas(16) u16 Ks[2][64][64];
    __shared__ alignas(16) u16 Vs[2][64][64];
    __shared__ alignas(16) u16 Pl[4][16][64];

    const int wg = blockIdx.x;
    const int xc = wg & 7;
    const int rm = wg >> 3;
    const int qx = rm & 15;
    const int bh = (rm >> 4) * 8 + xc;
    const int b = bh >> 4, h = bh & 15;
    const int q0 = qx * 128;
    const int tid = threadIdx.x, wid = tid >> 6, lane = tid & 63;
    const int ql = lane & 15, g = lane >> 4;
    const int qw = q0 + wid * 32;

    const u16* Qbh = Qp + (size_t)bh * 131072;
    const u16* Kbh = Kp + (size_t)bh * 131072;
    const u16* Vbh = Vt + (size_t)bh * 131072;
    const int* mrow = mask + b * 2048;

    char* KsB0 = (char*)Ks;
    char* VsB0 = (char*)Vs;
    char* PlB = (char*)Pl + wid * 2048;

    bf16x8 qf[2][2];
    #pragma unroll
    for (int fi = 0; fi < 2; fi++)
        #pragma unroll
        for (int ks = 0; ks < 2; ks++)
            qf[fi][ks] = *(const bf16x8*)&Qbh[(size_t)(qw + fi * 16 + ql) * 64 + ks * 32 + g * 8];

    f32x4 oacc[2][4] = {};
    float lrow[2] = {0.f, 0.f};
    const f32x4 kZero = {0.f, 0.f, 0.f, 0.f};

    int pwoff[4], proff[2];
    #pragma unroll
    for (int kb = 0; kb < 4; kb++)
        pwoff[kb] = ql * 128 + ((kb * 32 + g * 8) ^ ((ql & 7) << 4));
    #pragma unroll
    for (int ks = 0; ks < 2; ks++)
        proff[ks] = ql * 128 + ((ks * 64 + g * 16) ^ ((ql & 7) << 4));

    const int lrow8 = lane >> 3;
    const int coff  = ((lane & 7) ^ lrow8) << 4;
    const int rb    = wid * 16;

    auto stage = [&](int buf, int tt) {
        const size_t kv0 = (size_t)tt * 64;
        #pragma unroll
        for (int i = 0; i < 2; i++) {
            const int rt = rb + i * 8;
            gload_lds16((const char*)Kbh + (kv0 + rt + lrow8) * 128 + coff,
                        KsB0 + buf * 8192 + rt * 128);
            gload_lds16((const char*)Vbh + (size_t)(rt + lrow8) * 4096 + kv0 * 2 + coff,
                        VsB0 + buf * 8192 + rt * 128);
        }
    };

    stage(0, 0);
    int mcur = mrow[lane];
    __syncthreads();

    for (int t = 0; t < 32; ++t) {
        const int cur = t & 1, nxt = cur ^ 1;
        char* KsB = KsB0 + cur * 8192;
        char* VsB = VsB0 + cur * 8192;
        int mnxt = 1;
        if (t < 31) {
            stage(nxt, t + 1);
            mnxt = mrow[(t + 1) * 64 + lane];
        }
        const bool anym = (__ballot(mcur == 0) != 0ull);

        bf16x8 pf[2][2];
        #pragma unroll
        for (int fi = 0; fi < 2; fi++) {
            float ts = 0.f;
            __builtin_amdgcn_s_setprio(1);
            #pragma unroll
            for (int kb = 0; kb < 4; kb++) {
                const int row = kb * 16 + ql;
                const int swz = (row & 7) << 4;
                bf16x8 kf0 = *(const bf16x8*)(KsB + row * 128 + ((g * 16) ^ swz));
                bf16x8 kf1 = *(const bf16x8*)(KsB + row * 128 + ((64 + g * 16) ^ swz));
                f32x4 a = __builtin_amdgcn_mfma_f32_16x16x32_bf16(kf0, qf[fi][0], kZero, 0, 0, 0);
                a = __builtin_amdgcn_mfma_f32_16x16x32_bf16(kf1, qf[fi][1], a, 0, 0, 0);
                if (anym) {
                    int4 mi = *(const int4*)&mrow[t * 64 + kb * 16 + g * 4];
                    a[0] += mi.x ? 0.f : -1e30f;
                    a[1] += mi.y ? 0.f : -1e30f;
                    a[2] += mi.z ? 0.f : -1e30f;
                    a[3] += mi.w ? 0.f : -1e30f;
                }
                float p0 = EXP2(a[0]);
                float p1 = EXP2(a[1]);
                float p2 = EXP2(a[2]);
                float p3 = EXP2(a[3]);
                ts += (p0 + p1) + (p2 + p3);
                bf16x4 pb;
                pb[0] = (__bf16)p0; pb[1] = (__bf16)p1;
                pb[2] = (__bf16)p2; pb[3] = (__bf16)p3;
                *(bf16x4*)(PlB + pwoff[kb]) = pb;
            }
            __builtin_amdgcn_s_setprio(0);
            lrow[fi] += ts;
            pf[fi][0] = *(const bf16x8*)(PlB + proff[0]);
            pf[fi][1] = *(const bf16x8*)(PlB + proff[1]);
        }

        __builtin_amdgcn_s_setprio(1);
        #pragma unroll
        for (int dt = 0; dt < 4; dt++) {
            int row = dt * 16 + ql;
            int swz = (row & 7) << 4;
            bf16x8 vf0 = *(const bf16x8*)(VsB + row * 128 + ((g * 16) ^ swz));
            bf16x8 vf1 = *(const bf16x8*)(VsB + row * 128 + ((64 + g * 16) ^ swz));
            #pragma unroll
            for (int fi = 0; fi < 2; fi++) {
                oacc[fi][dt] = __builtin_amdgcn_mfma_f32_16x16x32_bf16(vf0, pf[fi][0], oacc[fi][dt], 0, 0, 0);
                oacc[fi][dt] = __builtin_amdgcn_mfma_f32_16x16x32_bf16(vf1, pf[fi][1], oacc[fi][dt], 0, 0, 0);
            }
        }
        __builtin_amdgcn_s_setprio(0);

        mcur = mnxt;
        __syncthreads();
    }

    #pragma unroll
    for (int fi = 0; fi < 2; fi++) {
        lrow[fi] += __shfl_xor(lrow[fi], 16, 64);
        lrow[fi] += __shfl_xor(lrow[fi], 32, 64);
        float inv = 1.f / lrow[fi];
        #pragma unroll
        for (int dt = 0; dt < 4; dt++) {
            bf16x4 ob;
            ob[0] = (__bf16)(oacc[fi][dt][0] * inv);
            ob[1] = (__bf16)(oacc[fi][dt][1] * inv);
            ob[2] = (__bf16)(oacc[fi][dt][2] * inv);
            ob[3] = (__bf16)(oacc[fi][dt][3] * inv);
            *(bf16x4*)(PlB + ql * 128 + ((dt * 32 + g * 8) ^ ((ql & 7) << 4))) = ob;
        }
        int rr = lane >> 2;
        int q = qw + fi * 16 + rr;
        #pragma unroll
        for (int pass = 0; pass < 2; pass++) {
            int cc = (lane & 3) + pass * 4;
            int4 val = *(const int4*)(PlB + rr * 128 + ((cc * 16) ^ ((rr & 7) << 4)));
            *(int4*)&O[((size_t)(b * 2048 + q)) * 1024 + h * 64 + cc * 8] = val;
        }
    }
}

// ---------------------------------------------------------------------------
// LayerNorm over last dim (1024), row per block, bf16 in / f32 out
// ---------------------------------------------------------------------------
__global__ __launch_bounds__(256) void ln_k(
    const u16* __restrict__ X, const float* __restrict__ gamma,
    const float* __restrict__ beta, float* __restrict__ out)
{
    const int row = blockIdx.x, tid = threadIdx.x;
    ushort4 u = ((const ushort4*)(X + (size_t)row * 1024))[tid];
    float v0 = bf2f(u.x), v1 = bf2f(u.y), v2 = bf2f(u.z), v3 = bf2f(u.w);
    float s = (v0 + v1) + (v2 + v3);
    float s2 = (v0 * v0 + v1 * v1) + (v2 * v2 + v3 * v3);
    #pragma unroll
    for (int off = 1; off < 64; off <<= 1) {
        s  += __shfl_xor(s, off, 64);
        s2 += __shfl_xor(s2, off, 64);
    }
    __shared__ float ss[4], ss2[4];
    int wid = tid >> 6;
    if ((tid & 63) == 0) { ss[wid] = s; ss2[wid] = s2; }
    __syncthreads();
    s = ss[0] + ss[1] + ss[2] + ss[3];
    s2 = ss2[0] + ss2[1] + ss2[2] + ss2[3];
    float mean = s * (1.f / 1024.f);
    float var = s2 * (1.f / 1024.f) - mean * mean;
    float rstd = rsqrtf(var + 1e-5f);
    float4 gm = ((const float4*)gamma)[tid];
    float4 be = ((const float4*)beta)[tid];
    float4 o;
    o.x = (v0 - mean) * rstd * gm.x + be.x;
    o.y = (v1 - mean) * rstd * gm.y + be.y;
    o.z = (v2 - mean) * rstd * gm.z + be.z;
    o.w = (v3 - mean) * rstd * gm.w + be.w;
    ((float4*)(out + (size_t)row * 1024))[tid] = o;
}

// ---------------------------------------------------------------------------
extern "C" void kernel_launch(void* const* d_in, const int* in_sizes, int n_in,
                              void* d_out, int out_size, void* d_ws, size_t ws_size,
                              hipStream_t stream)
{
    const float* queries = (const float*)d_in[0];
    const float* keys    = (const float*)d_in[1];
    const float* values  = (const float*)d_in[2];
    const int*   mask    = (const int*)d_in[3];
    const float* Wq = (const float*)d_in[4];
    const float* bq = (const float*)d_in[5];
    const float* Wk = (const float*)d_in[6];
    const float* bk = (const float*)d_in[7];
    const float* Wv = (const float*)d_in[8];
    const float* bv = (const float*)d_in[9];
    const float* Wo = (const float*)d_in[10];
    const float* bo = (const float*)d_in[11];
    const float* gamma = (const float*)d_in[12];
    const float* beta  = (const float*)d_in[13];

    u16* ws = (u16*)d_ws;
    u16* Wt = ws;                       // 4 x 1048576 u16 (8 MB)
    u16* Qp = ws + 4 * 1048576;         // 8388608 u16 each
    u16* Kp = Qp + 8388608;
    u16* Vt = Kp + 8388608;
    u16* O  = Vt + 8388608;
    u16* X  = Qp;                       // alias: Qp dead after attention (bf16 X)

    // Q pre-scale folds 1/sqrt(64) * log2(e) so softmax runs in exp2 domain
    const float qscale = 0.125f * 1.44269504088896f;

    transpose4<<<dim3(32, 32, 4), 256, 0, stream>>>(Wq, Wk, Wv, Wo, Wt);
    gemm_qkv<<<dim3(1536), 256, 0, stream>>>(queries, keys, values, Wt,
                                             bq, bk, bv, Qp, Kp, Vt, qscale);
    attn_k<<<dim3(1024), 256, 0, stream>>>(Qp, Kp, Vt, mask, O);
    gemm_o<<<dim3(512), 256, 0, stream>>>(O, Wt + 3145728, bo, queries, X);
    ln_k<<<8192, 256, 0, stream>>>(X, gamma, beta, (float*)d_out);
}

// Round 19
// 207.839 us; speedup vs baseline: 1.0726x; 1.0726x over previous
//
#include <hip/hip_runtime.h>

typedef __bf16 bf16x8 __attribute__((ext_vector_type(8)));
typedef __bf16 bf16x4 __attribute__((ext_vector_type(4)));
typedef float f32x4 __attribute__((ext_vector_type(4)));
typedef unsigned short u16;

#if __has_builtin(__builtin_amdgcn_exp2f)
#define EXP2(x) __builtin_amdgcn_exp2f(x)
#else
#define EXP2(x) exp2f(x)
#endif

__device__ __forceinline__ float bf2f(u16 u){
    union { unsigned int i; float f; } x; x.i = ((unsigned int)u) << 16; return x.f;
}
// native f32->bf16 (compiler emits v_cvt_pk_bf16_f32 for pairs)
__device__ __forceinline__ u16 bfbits(float f){
    __bf16 h = (__bf16)f;
    union { __bf16 b; u16 u; } x; x.b = h; return x.u;
}
__device__ __forceinline__ int4 cvt8(const float4 a, const float4 b){
    union { __bf16 h[8]; int4 v; } u;
    u.h[0] = (__bf16)a.x; u.h[1] = (__bf16)a.y; u.h[2] = (__bf16)a.z; u.h[3] = (__bf16)a.w;
    u.h[4] = (__bf16)b.x; u.h[5] = (__bf16)b.y; u.h[6] = (__bf16)b.z; u.h[7] = (__bf16)b.w;
    return u.v;
}
// async global->LDS, 16B per lane; dest is wave-uniform base (HW adds lane*16)
__device__ __forceinline__ void gload_lds16(const void* g, void* l){
    __builtin_amdgcn_global_load_lds(
        (const __attribute__((address_space(1))) unsigned int*)g,
        (__attribute__((address_space(3))) unsigned int*)l, 16, 0, 0);
}

// ---------------------------------------------------------------------------
// Transpose 4 x [1024][1024] f32 weights -> bf16 Wt [N][K]
// ---------------------------------------------------------------------------
__global__ __launch_bounds__(256) void transpose4(
    const float* __restrict__ w0, const float* __restrict__ w1,
    const float* __restrict__ w2, const float* __restrict__ w3,
    u16* __restrict__ out)
{
    __shared__ float tile[32][33];
    int mat = blockIdx.z;
    const float* in = (mat == 0) ? w0 : (mat == 1) ? w1 : (mat == 2) ? w2 : w3;
    u16* o = out + (size_t)mat * 1048576;
    int bx = blockIdx.x * 32, by = blockIdx.y * 32;
    int tx = threadIdx.x & 31, ty = threadIdx.x >> 5; // 32 x 8
    #pragma unroll
    for (int i = 0; i < 32; i += 8)
        tile[ty + i][tx] = in[(size_t)(by + ty + i) * 1024 + bx + tx];
    __syncthreads();
    #pragma unroll
    for (int i = 0; i < 32; i += 8)
        o[(size_t)(bx + ty + i) * 1024 + by + tx] = bfbits(tile[tx][ty + i]);
}

// ---------------------------------------------------------------------------
// Fused Q/K/V projection GEMM v4: 512 threads / 8 waves, wave tile 64x32
// -> acc[4][2] (32 acc regs), total regs <=128 -> 4 waves/SIMD (16/CU),
// double the residency of the 4-wave version (latency-bound at 2 waves/SIMD
// per R16-R18 evidence). BK=32, gload_lds B with (r>>1)&3 pre-XOR swizzle
// (R17-verified conflict-free), reg-staged f32->bf16 A (1 row/thread).
// seg 0/1 store [b][h][q][d] (seg0 scaled); seg 2 stores [b][h][d][q].
// ---------------------------------------------------------------------------
__global__ __launch_bounds__(512, 4) void gemm_qkv(
    const float* __restrict__ Aq, const float* __restrict__ Ak,
    const float* __restrict__ Avv, const u16* __restrict__ Wt3,
    const float* __restrict__ bq, const float* __restrict__ bk,
    const float* __restrict__ bv,
    u16* __restrict__ Qp, u16* __restrict__ Kp, u16* __restrict__ Vtd,
    float qscale)
{
    constexpr int K = 1024;
    __shared__ alignas(16) u16 smem[16384];      // 32 KB: As 2x8K | Bs 2x8K
    char* const AB = (char*)smem;
    auto Abase = [&](int buf){ return AB + buf * 8192; };
    auto Bbase = [&](int buf){ return AB + 16384 + buf * 8192; };

    const int tid = threadIdx.x;
    const int lane = tid & 63, wid = tid >> 6;   // 8 waves
    const int wm = wid >> 2, wn = wid & 3;       // 2 x 4 wave grid

    const int wg = blockIdx.x;                   // 0..1535
    const int seg = wg >> 9;                     // 0..2
    const int w = wg & 511;
    const int xcd = w & 7, rest = w >> 3;
    const int ntile = rest & 7, mhi = rest >> 3;
    const int m0 = (mhi * 8 + xcd) * 128;
    const int n0 = ntile * 128;

    const float* A = (seg == 0) ? Aq : (seg == 1) ? Ak : Avv;
    const u16* Bt = Wt3 + (size_t)seg * 1048576;
    const float* bias = (seg == 0) ? bq : (seg == 1) ? bk : bv;
    const float scale = (seg == 0) ? qscale : 1.0f;
    u16* Cv = (seg == 0) ? Qp : (seg == 1) ? Kp : Vtd;
    const bool vmode = (seg == 2);

    const int r0 = tid >> 2;            // A row 0..127 (one row per thread)
    const int cq = tid & 3;             // col-quarter: 8 f32 each
    const int fr = lane & 15;
    const int fkB = (lane >> 4) * 16;

    const float* Af = A + (size_t)(m0 + r0) * K + cq * 8;
    const int aswz = ((r0 >> 1) & 3) << 4;

    // B stage: 1 inst/wave, 16 rows (1 KB); dest linear [row][chunk],
    // source chunk pre-XORed with (row>>1)&3
    auto stageB = [&](int buf, int tcol) {
        int r = wid * 16 + (lane >> 2);
        gload_lds16(Bt + (size_t)(n0 + r) * K + tcol + ((lane & 3) ^ ((r >> 1) & 3)) * 8,
                    Bbase(buf) + wid * 1024);
    };

    // prologue
    stageB(0, 0);
    {
        const float4* p = (const float4*)Af;
        *(int4*)(Abase(0) + r0 * 64 + ((cq * 16) ^ aswz)) = cvt8(p[0], p[1]);
    }
    __syncthreads();

    f32x4 acc[4][2] = {};
    constexpr int NT = K / 32;
    for (int t = 0; t < NT; ++t) {
        const int cur = t & 1, nxt = cur ^ 1;
        float4 a0, a1;
        if (t + 1 < NT) {
            stageB(nxt, (t + 1) * 32);
            a0 = ((const float4*)(Af + (t + 1) * 32))[0];
            a1 = ((const float4*)(Af + (t + 1) * 32))[1];
        }
        bf16x8 af[4], bfr[2];
        #pragma unroll
        for (int i = 0; i < 4; i++) {
            int ra = wm * 64 + i * 16 + fr;
            af[i] = *(const bf16x8*)(Abase(cur) + ra * 64 + (fkB ^ (((ra >> 1) & 3) << 4)));
        }
        #pragma unroll
        for (int j = 0; j < 2; j++) {
            int rb = wn * 32 + j * 16 + fr;
            bfr[j] = *(const bf16x8*)(Bbase(cur) + rb * 64 + (fkB ^ (((rb >> 1) & 3) << 4)));
        }
        #pragma unroll
        for (int mi = 0; mi < 4; mi++)
            #pragma unroll
            for (int ni = 0; ni < 2; ni++)
                acc[mi][ni] = __builtin_amdgcn_mfma_f32_16x16x32_bf16(
                    af[mi], bfr[ni], acc[mi][ni], 0, 0, 0);
        if (t + 1 < NT) {
            *(int4*)(Abase(nxt) + r0 * 64 + ((cq * 16) ^ aswz)) = cvt8(a0, a1);
        }
        __syncthreads();
    }

    // epilogue: acc -> Ct (bf16, swizzled, aliases As/Bs) -> coalesced stores
    char* const CtB = AB;   // [128][128] u16 = 32 KB
    #pragma unroll
    for (int ni = 0; ni < 2; ni++) {
        int nn = wn * 32 + ni * 16 + fr;
        float bcol = bias[n0 + nn];
        #pragma unroll
        for (int mi = 0; mi < 4; mi++) {
            #pragma unroll
            for (int r = 0; r < 4; r++) {
                int mm = wm * 64 + mi * 16 + (lane >> 4) * 4 + r;
                float val = (acc[mi][ni][r] + bcol) * scale;
                int row  = vmode ? nn : mm;
                int colb = (vmode ? mm : nn) * 2;
                *(u16*)(CtB + row * 256 +
                        ((colb & 15) | ((((colb >> 4)) ^ (row & 7)) << 4))) = bfbits(val);
            }
        }
    }
    __syncthreads();
    #pragma unroll
    for (int p = 0; p < 4; p++) {
        int idx = p * 512 + tid;
        int row = idx >> 4, ck = idx & 15;
        int4 val = *(const int4*)(CtB + row * 256 + ((ck ^ (row & 7)) << 4));
        if (vmode) {
            int n = n0 + row, m = m0 + ck * 8;
            int h = n >> 6, d = n & 63, bb = m >> 11, q = m & 2047;
            *(int4*)&Cv[(size_t)(bb * 16 + h) * 131072 + (size_t)d * 2048 + q] = val;
        } else {
            int m = m0 + row, n = n0 + ck * 8;
            int h = n >> 6, d = n & 63, bb = m >> 11, q = m & 2047;
            *(int4*)&Cv[(size_t)(bb * 16 + h) * 131072 + (size_t)q * 64 + d] = val;
        }
    }
}

// ---------------------------------------------------------------------------
// O-projection GEMM (bf16 A via gload_lds, f32 residual, bf16 row-major out)
// (row>>1)&3 swizzle (conflict-free, R17-verified). Unchanged.
// ---------------------------------------------------------------------------
__global__ __launch_bounds__(256) void gemm_o(
    const u16* __restrict__ Ah, const u16* __restrict__ Bt,
    const float* __restrict__ bias, const float* __restrict__ resid,
    u16* __restrict__ Cv)
{
    constexpr int K = 1024;
    __shared__ alignas(16) u16 smem[16384];
    char* const AB = (char*)smem;
    auto Abase = [&](int buf){ return AB + buf * 8192; };
    auto Bbase = [&](int buf){ return AB + 16384 + buf * 8192; };

    const int tid = threadIdx.x;
    const int lane = tid & 63, wid = tid >> 6;
    const int wm = wid >> 1, wn = wid & 1;

    const int wg = blockIdx.x;                   // 0..511
    const int xcd = wg & 7, rest = wg >> 3;
    const int ntile = rest & 7, mhi = rest >> 3;
    const int m0 = (mhi * 8 + xcd) * 128;
    const int n0 = ntile * 128;

    const int fr = lane & 15;
    const int fkB = (lane >> 4) * 16;

    const int srow = lane >> 2;
    auto stageB = [&](int buf, int tcol) {
        #pragma unroll
        for (int i = 0; i < 2; i++) {
            int rt = wid * 32 + i * 16;
            int r = rt + srow;
            gload_lds16(Bt + (size_t)(n0 + r) * K + tcol + ((lane & 3) ^ ((r >> 1) & 3)) * 8,
                        Bbase(buf) + rt * 64);
        }
    };
    auto stageA = [&](int buf, int tcol) {
        #pragma unroll
        for (int i = 0; i < 2; i++) {
            int rt = wid * 32 + i * 16;
            int r = rt + srow;
            gload_lds16(Ah + (size_t)(m0 + r) * K + tcol + ((lane & 3) ^ ((r >> 1) & 3)) * 8,
                        Abase(buf) + rt * 64);
        }
    };

    stageB(0, 0);
    stageA(0, 0);
    __syncthreads();

    f32x4 acc[4][4] = {};
    constexpr int NT = K / 32;
    for (int t = 0; t < NT; ++t) {
        const int cur = t & 1, nxt = cur ^ 1;
        if (t + 1 < NT) {
            stageB(nxt, (t + 1) * 32);
            stageA(nxt, (t + 1) * 32);
        }
        bf16x8 af[4], bfr[4];
        #pragma unroll
        for (int i = 0; i < 4; i++) {
            int ra = wm * 64 + i * 16 + fr;
            int rb = wn * 64 + i * 16 + fr;
            af[i]  = *(const bf16x8*)(Abase(cur) + ra * 64 + (fkB ^ (((ra >> 1) & 3) << 4)));
            bfr[i] = *(const bf16x8*)(Bbase(cur) + rb * 64 + (fkB ^ (((rb >> 1) & 3) << 4)));
        }
        #pragma unroll
        for (int mi = 0; mi < 4; mi++)
            #pragma unroll
            for (int ni = 0; ni < 4; ni++)
                acc[mi][ni] = __builtin_amdgcn_mfma_f32_16x16x32_bf16(
                    af[mi], bfr[ni], acc[mi][ni], 0, 0, 0);
        __syncthreads();
    }

    char* const CtB = AB;
    #pragma unroll
    for (int ni = 0; ni < 4; ni++) {
        int nn = wn * 64 + ni * 16 + fr;
        float bcol = bias[n0 + nn];
        #pragma unroll
        for (int mi = 0; mi < 4; mi++) {
            #pragma unroll
            for (int r = 0; r < 4; r++) {
                int mm = wm * 64 + mi * 16 + (lane >> 4) * 4 + r;
                float val = acc[mi][ni][r] + bcol + resid[(size_t)(m0 + mm) * 1024 + n0 + nn];
                int colb = nn * 2;
                *(u16*)(CtB + mm * 256 +
                        ((colb & 15) | ((((colb >> 4)) ^ (mm & 7)) << 4))) = bfbits(val);
            }
        }
    }
    __syncthreads();
    #pragma unroll
    for (int p = 0; p < 8; p++) {
        int idx = p * 256 + tid;
        int row = idx >> 4, ck = idx & 15;
        int4 val = *(const int4*)(CtB + row * 256 + ((ck ^ (row & 7)) << 4));
        *(int4*)&Cv[(size_t)(m0 + row) * 1024 + n0 + ck * 8] = val;
    }
}

// ---------------------------------------------------------------------------
// Flash attention v7: swapped QK^T with fused per-kb exp2, softmax-lite,
// gload_lds K/V staging, XCD-bijective swizzle, 4 blocks/CU. (unchanged)
// ---------------------------------------------------------------------------
__global__ __launch_bounds__(256, 4) void attn_k(
    const u16* __restrict__ Qp, const u16* __restrict__ Kp,
    const u16* __restrict__ Vt, const int* __restrict__ mask,
    u16* __restrict__ O)
{
    __shared__ alignas(16) u16 Ks[2][64][64];
    __shared__ alignas(16) u16 Vs[2][64][64];
    __shared__ alignas(16) u16 Pl[4][16][64];

    const int wg = blockIdx.x;
    const int xc = wg & 7;
    const int rm = wg >> 3;
    const int qx = rm & 15;
    const int bh = (rm >> 4) * 8 + xc;
    const int b = bh >> 4, h = bh & 15;
    const int q0 = qx * 128;
    const int tid = threadIdx.x, wid = tid >> 6, lane = tid & 63;
    const int ql = lane & 15, g = lane >> 4;
    const int qw = q0 + wid * 32;

    const u16* Qbh = Qp + (size_t)bh * 131072;
    const u16* Kbh = Kp + (size_t)bh * 131072;
    const u16* Vbh = Vt + (size_t)bh * 131072;
    const int* mrow = mask + b * 2048;

    char* KsB0 = (char*)Ks;
    char* VsB0 = (char*)Vs;
    char* PlB = (char*)Pl + wid * 2048;

    bf16x8 qf[2][2];
    #pragma unroll
    for (int fi = 0; fi < 2; fi++)
        #pragma unroll
        for (int ks = 0; ks < 2; ks++)
            qf[fi][ks] = *(const bf16x8*)&Qbh[(size_t)(qw + fi * 16 + ql) * 64 + ks * 32 + g * 8];

    f32x4 oacc[2][4] = {};
    float lrow[2] = {0.f, 0.f};
    const f32x4 kZero = {0.f, 0.f, 0.f, 0.f};

    int pwoff[4], proff[2];
    #pragma unroll
    for (int kb = 0; kb < 4; kb++)
        pwoff[kb] = ql * 128 + ((kb * 32 + g * 8) ^ ((ql & 7) << 4));
    #pragma unroll
    for (int ks = 0; ks < 2; ks++)
        proff[ks] = ql * 128 + ((ks * 64 + g * 16) ^ ((ql & 7) << 4));

    const int lrow8 = lane >> 3;
    const int coff  = ((lane & 7) ^ lrow8) << 4;
    const int rb    = wid * 16;

    auto stage = [&](int buf, int tt) {
        const size_t kv0 = (size_t)tt * 64;
        #pragma unroll
        for (int i = 0; i < 2; i++) {
            const int rt = rb + i * 8;
            gload_lds16((const char*)Kbh + (kv0 + rt + lrow8) * 128 + coff,
                        KsB0 + buf * 8192 + rt * 128);
            gload_lds16((const char*)Vbh + (size_t)(rt + lrow8) * 4096 + kv0 * 2 + coff,
                        VsB0 + buf * 8192 + rt * 128);
        }
    };

    stage(0, 0);
    int mcur = mrow[lane];
    __syncthreads();

    for (int t = 0; t < 32; ++t) {
        const int cur = t & 1, nxt = cur ^ 1;
        char* KsB = KsB0 + cur * 8192;
        char* VsB = VsB0 + cur * 8192;
        int mnxt = 1;
        if (t < 31) {
            stage(nxt, t + 1);
            mnxt = mrow[(t + 1) * 64 + lane];
        }
        const bool anym = (__ballot(mcur == 0) != 0ull);

        bf16x8 pf[2][2];
        #pragma unroll
        for (int fi = 0; fi < 2; fi++) {
            float ts = 0.f;
            __builtin_amdgcn_s_setprio(1);
            #pragma unroll
            for (int kb = 0; kb < 4; kb++) {
                const int row = kb * 16 + ql;
                const int swz = (row & 7) << 4;
                bf16x8 kf0 = *(const bf16x8*)(KsB + row * 128 + ((g * 16) ^ swz));
                bf16x8 kf1 = *(const bf16x8*)(KsB + row * 128 + ((64 + g * 16) ^ swz));
                f32x4 a = __builtin_amdgcn_mfma_f32_16x16x32_bf16(kf0, qf[fi][0], kZero, 0, 0, 0);
                a = __builtin_amdgcn_mfma_f32_16x16x32_bf16(kf1, qf[fi][1], a, 0, 0, 0);
                if (anym) {
                    int4 mi = *(const int4*)&mrow[t * 64 + kb * 16 + g * 4];
                    a[0] += mi.x ? 0.f : -1e30f;
                    a[1] += mi.y ? 0.f : -1e30f;
                    a[2] += mi.z ? 0.f : -1e30f;
                    a[3] += mi.w ? 0.f : -1e30f;
                }
                float p0 = EXP2(a[0]);
                float p1 = EXP2(a[1]);
                float p2 = EXP2(a[2]);
                float p3 = EXP2(a[3]);
                ts += (p0 + p1) + (p2 + p3);
                bf16x4 pb;
                pb[0] = (__bf16)p0; pb[1] = (__bf16)p1;
                pb[2] = (__bf16)p2; pb[3] = (__bf16)p3;
                *(bf16x4*)(PlB + pwoff[kb]) = pb;
            }
            __builtin_amdgcn_s_setprio(0);
            lrow[fi] += ts;
            pf[fi][0] = *(const bf16x8*)(PlB + proff[0]);
            pf[fi][1] = *(const bf16x8*)(PlB + proff[1]);
        }

        __builtin_amdgcn_s_setprio(1);
        #pragma unroll
        for (int dt = 0; dt < 4; dt++) {
            int row = dt * 16 + ql;
            int swz = (row & 7) << 4;
            bf16x8 vf0 = *(const bf16x8*)(VsB + row * 128 + ((g * 16) ^ swz));
            bf16x8 vf1 = *(const bf16x8*)(VsB + row * 128 + ((64 + g * 16) ^ swz));
            #pragma unroll
            for (int fi = 0; fi < 2; fi++) {
                oacc[fi][dt] = __builtin_amdgcn_mfma_f32_16x16x32_bf16(vf0, pf[fi][0], oacc[fi][dt], 0, 0, 0);
                oacc[fi][dt] = __builtin_amdgcn_mfma_f32_16x16x32_bf16(vf1, pf[fi][1], oacc[fi][dt], 0, 0, 0);
            }
        }
        __builtin_amdgcn_s_setprio(0);

        mcur = mnxt;
        __syncthreads();
    }

    #pragma unroll
    for (int fi = 0; fi < 2; fi++) {
        lrow[fi] += __shfl_xor(lrow[fi], 16, 64);
        lrow[fi] += __shfl_xor(lrow[fi], 32, 64);
        float inv = 1.f / lrow[fi];
        #pragma unroll
        for (int dt = 0; dt < 4; dt++) {
            bf16x4 ob;
            ob[0] = (__bf16)(oacc[fi][dt][0] * inv);
            ob[1] = (__bf16)(oacc[fi][dt][1] * inv);
            ob[2] = (__bf16)(oacc[fi][dt][2] * inv);
            ob[3] = (__bf16)(oacc[fi][dt][3] * inv);
            *(bf16x4*)(PlB + ql * 128 + ((dt * 32 + g * 8) ^ ((ql & 7) << 4))) = ob;
        }
        int rr = lane >> 2;
        int q = qw + fi * 16 + rr;
        #pragma unroll
        for (int pass = 0; pass < 2; pass++) {
            int cc = (lane & 3) + pass * 4;
            int4 val = *(const int4*)(PlB + rr * 128 + ((cc * 16) ^ ((rr & 7) << 4)));
            *(int4*)&O[((size_t)(b * 2048 + q)) * 1024 + h * 64 + cc * 8] = val;
        }
    }
}

// ---------------------------------------------------------------------------
// LayerNorm over last dim (1024), row per block, bf16 in / f32 out
// ---------------------------------------------------------------------------
__global__ __launch_bounds__(256) void ln_k(
    const u16* __restrict__ X, const float* __restrict__ gamma,
    const float* __restrict__ beta, float* __restrict__ out)
{
    const int row = blockIdx.x, tid = threadIdx.x;
    ushort4 u = ((const ushort4*)(X + (size_t)row * 1024))[tid];
    float v0 = bf2f(u.x), v1 = bf2f(u.y), v2 = bf2f(u.z), v3 = bf2f(u.w);
    float s = (v0 + v1) + (v2 + v3);
    float s2 = (v0 * v0 + v1 * v1) + (v2 * v2 + v3 * v3);
    #pragma unroll
    for (int off = 1; off < 64; off <<= 1) {
        s  += __shfl_xor(s, off, 64);
        s2 += __shfl_xor(s2, off, 64);
    }
    __shared__ float ss[4], ss2[4];
    int wid = tid >> 6;
    if ((tid & 63) == 0) { ss[wid] = s; ss2[wid] = s2; }
    __syncthreads();
    s = ss[0] + ss[1] + ss[2] + ss[3];
    s2 = ss2[0] + ss2[1] + ss2[2] + ss2[3];
    float mean = s * (1.f / 1024.f);
    float var = s2 * (1.f / 1024.f) - mean * mean;
    float rstd = rsqrtf(var + 1e-5f);
    float4 gm = ((const float4*)gamma)[tid];
    float4 be = ((const float4*)beta)[tid];
    float4 o;
    o.x = (v0 - mean) * rstd * gm.x + be.x;
    o.y = (v1 - mean) * rstd * gm.y + be.y;
    o.z = (v2 - mean) * rstd * gm.z + be.z;
    o.w = (v3 - mean) * rstd * gm.w + be.w;
    ((float4*)(out + (size_t)row * 1024))[tid] = o;
}

// ---------------------------------------------------------------------------
extern "C" void kernel_launch(void* const* d_in, const int* in_sizes, int n_in,
                              void* d_out, int out_size, void* d_ws, size_t ws_size,
                              hipStream_t stream)
{
    const float* queries = (const float*)d_in[0];
    const float* keys    = (const float*)d_in[1];
    const float* values  = (const float*)d_in[2];
    const int*   mask    = (const int*)d_in[3];
    const float* Wq = (const float*)d_in[4];
    const float* bq = (const float*)d_in[5];
    const float* Wk = (const float*)d_in[6];
    const float* bk = (const float*)d_in[7];
    const float* Wv = (const float*)d_in[8];
    const float* bv = (const float*)d_in[9];
    const float* Wo = (const float*)d_in[10];
    const float* bo = (const float*)d_in[11];
    const float* gamma = (const float*)d_in[12];
    const float* beta  = (const float*)d_in[13];

    u16* ws = (u16*)d_ws;
    u16* Wt = ws;                       // 4 x 1048576 u16 (8 MB)
    u16* Qp = ws + 4 * 1048576;         // 8388608 u16 each
    u16* Kp = Qp + 8388608;
    u16* Vt = Kp + 8388608;
    u16* O  = Vt + 8388608;
    u16* X  = Qp;                       // alias: Qp dead after attention (bf16 X)

    // Q pre-scale folds 1/sqrt(64) * log2(e) so softmax runs in exp2 domain
    const float qscale = 0.125f * 1.44269504088896f;

    transpose4<<<dim3(32, 32, 4), 256, 0, stream>>>(Wq, Wk, Wv, Wo, Wt);
    gemm_qkv<<<dim3(1536), 512, 0, stream>>>(queries, keys, values, Wt,
                                             bq, bk, bv, Qp, Kp, Vt, qscale);
    attn_k<<<dim3(1024), 256, 0, stream>>>(Qp, Kp, Vt, mask, O);
    gemm_o<<<dim3(512), 256, 0, stream>>>(O, Wt + 3145728, bo, queries, X);
    ln_k<<<8192, 256, 0, stream>>>(X, gamma, beta, (float*)d_out);
}

// Round 20
// 205.728 us; speedup vs baseline: 1.0837x; 1.0103x over previous
//
#include <hip/hip_runtime.h>

typedef __bf16 bf16x8 __attribute__((ext_vector_type(8)));
typedef __bf16 bf16x4 __attribute__((ext_vector_type(4)));
typedef float f32x4 __attribute__((ext_vector_type(4)));
typedef unsigned short u16;

#if __has_builtin(__builtin_amdgcn_exp2f)
#define EXP2(x) __builtin_amdgcn_exp2f(x)
#else
#define EXP2(x) exp2f(x)
#endif

__device__ __forceinline__ float bf2f(u16 u){
    union { unsigned int i; float f; } x; x.i = ((unsigned int)u) << 16; return x.f;
}
// native f32->bf16 (compiler emits v_cvt_pk_bf16_f32 for pairs)
__device__ __forceinline__ u16 bfbits(float f){
    __bf16 h = (__bf16)f;
    union { __bf16 b; u16 u; } x; x.b = h; return x.u;
}
__device__ __forceinline__ int4 cvt8(const float4 a, const float4 b){
    union { __bf16 h[8]; int4 v; } u;
    u.h[0] = (__bf16)a.x; u.h[1] = (__bf16)a.y; u.h[2] = (__bf16)a.z; u.h[3] = (__bf16)a.w;
    u.h[4] = (__bf16)b.x; u.h[5] = (__bf16)b.y; u.h[6] = (__bf16)b.z; u.h[7] = (__bf16)b.w;
    return u.v;
}
// async global->LDS, 16B per lane; dest is wave-uniform base (HW adds lane*16)
__device__ __forceinline__ void gload_lds16(const void* g, void* l){
    __builtin_amdgcn_global_load_lds(
        (const __attribute__((address_space(1))) unsigned int*)g,
        (__attribute__((address_space(3))) unsigned int*)l, 16, 0, 0);
}

// ---------------------------------------------------------------------------
// Transpose 4 x [1024][1024] f32 weights -> bf16 Wt [N][K]
// ---------------------------------------------------------------------------
__global__ __launch_bounds__(256) void transpose4(
    const float* __restrict__ w0, const float* __restrict__ w1,
    const float* __restrict__ w2, const float* __restrict__ w3,
    u16* __restrict__ out)
{
    __shared__ float tile[32][33];
    int mat = blockIdx.z;
    const float* in = (mat == 0) ? w0 : (mat == 1) ? w1 : (mat == 2) ? w2 : w3;
    u16* o = out + (size_t)mat * 1048576;
    int bx = blockIdx.x * 32, by = blockIdx.y * 32;
    int tx = threadIdx.x & 31, ty = threadIdx.x >> 5; // 32 x 8
    #pragma unroll
    for (int i = 0; i < 32; i += 8)
        tile[ty + i][tx] = in[(size_t)(by + ty + i) * 1024 + bx + tx];
    __syncthreads();
    #pragma unroll
    for (int i = 0; i < 32; i += 8)
        o[(size_t)(bx + ty + i) * 1024 + by + tx] = bfbits(tile[tx][ty + i]);
}

// ---------------------------------------------------------------------------
// Fused Q/K/V projection GEMM v4 (R19-verified): 512 threads / 8 waves,
// wave tile 64x32, acc[4][2], total regs ~68 -> 4 waves/SIMD. BK=32,
// gload_lds B with (r>>1)&3 pre-XOR swizzle, reg-staged f32->bf16 A.
// seg 0/1 store [b][h][q][d] (seg0 scaled); seg 2 stores [b][h][d][q].
// ---------------------------------------------------------------------------
__global__ __launch_bounds__(512, 4) void gemm_qkv(
    const float* __restrict__ Aq, const float* __restrict__ Ak,
    const float* __restrict__ Avv, const u16* __restrict__ Wt3,
    const float* __restrict__ bq, const float* __restrict__ bk,
    const float* __restrict__ bv,
    u16* __restrict__ Qp, u16* __restrict__ Kp, u16* __restrict__ Vtd,
    float qscale)
{
    constexpr int K = 1024;
    __shared__ alignas(16) u16 smem[16384];      // 32 KB: As 2x8K | Bs 2x8K
    char* const AB = (char*)smem;
    auto Abase = [&](int buf){ return AB + buf * 8192; };
    auto Bbase = [&](int buf){ return AB + 16384 + buf * 8192; };

    const int tid = threadIdx.x;
    const int lane = tid & 63, wid = tid >> 6;   // 8 waves
    const int wm = wid >> 2, wn = wid & 3;       // 2 x 4 wave grid

    const int wg = blockIdx.x;                   // 0..1535
    const int seg = wg >> 9;                     // 0..2
    const int w = wg & 511;
    const int xcd = w & 7, rest = w >> 3;
    const int ntile = rest & 7, mhi = rest >> 3;
    const int m0 = (mhi * 8 + xcd) * 128;
    const int n0 = ntile * 128;

    const float* A = (seg == 0) ? Aq : (seg == 1) ? Ak : Avv;
    const u16* Bt = Wt3 + (size_t)seg * 1048576;
    const float* bias = (seg == 0) ? bq : (seg == 1) ? bk : bv;
    const float scale = (seg == 0) ? qscale : 1.0f;
    u16* Cv = (seg == 0) ? Qp : (seg == 1) ? Kp : Vtd;
    const bool vmode = (seg == 2);

    const int r0 = tid >> 2;            // A row 0..127 (one row per thread)
    const int cq = tid & 3;             // col-quarter: 8 f32 each
    const int fr = lane & 15;
    const int fkB = (lane >> 4) * 16;

    const float* Af = A + (size_t)(m0 + r0) * K + cq * 8;
    const int aswz = ((r0 >> 1) & 3) << 4;

    // B stage: 1 inst/wave, 16 rows (1 KB); source chunk pre-XORed
    auto stageB = [&](int buf, int tcol) {
        int r = wid * 16 + (lane >> 2);
        gload_lds16(Bt + (size_t)(n0 + r) * K + tcol + ((lane & 3) ^ ((r >> 1) & 3)) * 8,
                    Bbase(buf) + wid * 1024);
    };

    // prologue
    stageB(0, 0);
    {
        const float4* p = (const float4*)Af;
        *(int4*)(Abase(0) + r0 * 64 + ((cq * 16) ^ aswz)) = cvt8(p[0], p[1]);
    }
    __syncthreads();

    f32x4 acc[4][2] = {};
    constexpr int NT = K / 32;
    for (int t = 0; t < NT; ++t) {
        const int cur = t & 1, nxt = cur ^ 1;
        float4 a0, a1;
        if (t + 1 < NT) {
            stageB(nxt, (t + 1) * 32);
            a0 = ((const float4*)(Af + (t + 1) * 32))[0];
            a1 = ((const float4*)(Af + (t + 1) * 32))[1];
        }
        bf16x8 af[4], bfr[2];
        #pragma unroll
        for (int i = 0; i < 4; i++) {
            int ra = wm * 64 + i * 16 + fr;
            af[i] = *(const bf16x8*)(Abase(cur) + ra * 64 + (fkB ^ (((ra >> 1) & 3) << 4)));
        }
        #pragma unroll
        for (int j = 0; j < 2; j++) {
            int rb = wn * 32 + j * 16 + fr;
            bfr[j] = *(const bf16x8*)(Bbase(cur) + rb * 64 + (fkB ^ (((rb >> 1) & 3) << 4)));
        }
        #pragma unroll
        for (int mi = 0; mi < 4; mi++)
            #pragma unroll
            for (int ni = 0; ni < 2; ni++)
                acc[mi][ni] = __builtin_amdgcn_mfma_f32_16x16x32_bf16(
                    af[mi], bfr[ni], acc[mi][ni], 0, 0, 0);
        if (t + 1 < NT) {
            *(int4*)(Abase(nxt) + r0 * 64 + ((cq * 16) ^ aswz)) = cvt8(a0, a1);
        }
        __syncthreads();
    }

    // epilogue: acc -> Ct (bf16, swizzled, aliases As/Bs) -> coalesced stores
    char* const CtB = AB;   // [128][128] u16 = 32 KB
    #pragma unroll
    for (int ni = 0; ni < 2; ni++) {
        int nn = wn * 32 + ni * 16 + fr;
        float bcol = bias[n0 + nn];
        #pragma unroll
        for (int mi = 0; mi < 4; mi++) {
            #pragma unroll
            for (int r = 0; r < 4; r++) {
                int mm = wm * 64 + mi * 16 + (lane >> 4) * 4 + r;
                float val = (acc[mi][ni][r] + bcol) * scale;
                int row  = vmode ? nn : mm;
                int colb = (vmode ? mm : nn) * 2;
                *(u16*)(CtB + row * 256 +
                        ((colb & 15) | ((((colb >> 4)) ^ (row & 7)) << 4))) = bfbits(val);
            }
        }
    }
    __syncthreads();
    #pragma unroll
    for (int p = 0; p < 4; p++) {
        int idx = p * 512 + tid;
        int row = idx >> 4, ck = idx & 15;
        int4 val = *(const int4*)(CtB + row * 256 + ((ck ^ (row & 7)) << 4));
        if (vmode) {
            int n = n0 + row, m = m0 + ck * 8;
            int h = n >> 6, d = n & 63, bb = m >> 11, q = m & 2047;
            *(int4*)&Cv[(size_t)(bb * 16 + h) * 131072 + (size_t)d * 2048 + q] = val;
        } else {
            int m = m0 + row, n = n0 + ck * 8;
            int h = n >> 6, d = n & 63, bb = m >> 11, q = m & 2047;
            *(int4*)&Cv[(size_t)(bb * 16 + h) * 131072 + (size_t)q * 64 + d] = val;
        }
    }
}

// ---------------------------------------------------------------------------
// O-projection GEMM v2: same 512-thread/8-wave structure (wave tile 64x32,
// acc[4][2], both operands via gload_lds, zero staging registers).
// bf16 A, f32 residual, bf16 row-major out. Grid 512 -> 2 blocks/CU x 8
// waves = 16 waves/CU (was 8).
// ---------------------------------------------------------------------------
__global__ __launch_bounds__(512, 4) void gemm_o(
    const u16* __restrict__ Ah, const u16* __restrict__ Bt,
    const float* __restrict__ bias, const float* __restrict__ resid,
    u16* __restrict__ Cv)
{
    constexpr int K = 1024;
    __shared__ alignas(16) u16 smem[16384];      // 32 KB: As 2x8K | Bs 2x8K
    char* const AB = (char*)smem;
    auto Abase = [&](int buf){ return AB + buf * 8192; };
    auto Bbase = [&](int buf){ return AB + 16384 + buf * 8192; };

    const int tid = threadIdx.x;
    const int lane = tid & 63, wid = tid >> 6;   // 8 waves
    const int wm = wid >> 2, wn = wid & 3;       // 2 x 4 wave grid

    const int wg = blockIdx.x;                   // 0..511
    const int xcd = wg & 7, rest = wg >> 3;
    const int ntile = rest & 7, mhi = rest >> 3;
    const int m0 = (mhi * 8 + xcd) * 128;
    const int n0 = ntile * 128;

    const int fr = lane & 15;
    const int fkB = (lane >> 4) * 16;

    auto stageB = [&](int buf, int tcol) {
        int r = wid * 16 + (lane >> 2);
        gload_lds16(Bt + (size_t)(n0 + r) * K + tcol + ((lane & 3) ^ ((r >> 1) & 3)) * 8,
                    Bbase(buf) + wid * 1024);
    };
    auto stageA = [&](int buf, int tcol) {
        int r = wid * 16 + (lane >> 2);
        gload_lds16(Ah + (size_t)(m0 + r) * K + tcol + ((lane & 3) ^ ((r >> 1) & 3)) * 8,
                    Abase(buf) + wid * 1024);
    };

    stageB(0, 0);
    stageA(0, 0);
    __syncthreads();

    f32x4 acc[4][2] = {};
    constexpr int NT = K / 32;
    for (int t = 0; t < NT; ++t) {
        const int cur = t & 1, nxt = cur ^ 1;
        if (t + 1 < NT) {
            stageB(nxt, (t + 1) * 32);
            stageA(nxt, (t + 1) * 32);
        }
        bf16x8 af[4], bfr[2];
        #pragma unroll
        for (int i = 0; i < 4; i++) {
            int ra = wm * 64 + i * 16 + fr;
            af[i] = *(const bf16x8*)(Abase(cur) + ra * 64 + (fkB ^ (((ra >> 1) & 3) << 4)));
        }
        #pragma unroll
        for (int j = 0; j < 2; j++) {
            int rb = wn * 32 + j * 16 + fr;
            bfr[j] = *(const bf16x8*)(Bbase(cur) + rb * 64 + (fkB ^ (((rb >> 1) & 3) << 4)));
        }
        #pragma unroll
        for (int mi = 0; mi < 4; mi++)
            #pragma unroll
            for (int ni = 0; ni < 2; ni++)
                acc[mi][ni] = __builtin_amdgcn_mfma_f32_16x16x32_bf16(
                    af[mi], bfr[ni], acc[mi][ni], 0, 0, 0);
        __syncthreads();
    }

    // epilogue: acc + bias + residual -> Ct (bf16, swizzled) -> coalesced
    char* const CtB = AB;
    #pragma unroll
    for (int ni = 0; ni < 2; ni++) {
        int nn = wn * 32 + ni * 16 + fr;
        float bcol = bias[n0 + nn];
        #pragma unroll
        for (int mi = 0; mi < 4; mi++) {
            #pragma unroll
            for (int r = 0; r < 4; r++) {
                int mm = wm * 64 + mi * 16 + (lane >> 4) * 4 + r;
                float val = acc[mi][ni][r] + bcol + resid[(size_t)(m0 + mm) * 1024 + n0 + nn];
                int colb = nn * 2;
                *(u16*)(CtB + mm * 256 +
                        ((colb & 15) | ((((colb >> 4)) ^ (mm & 7)) << 4))) = bfbits(val);
            }
        }
    }
    __syncthreads();
    #pragma unroll
    for (int p = 0; p < 4; p++) {
        int idx = p * 512 + tid;
        int row = idx >> 4, ck = idx & 15;
        int4 val = *(const int4*)(CtB + row * 256 + ((ck ^ (row & 7)) << 4));
        *(int4*)&Cv[(size_t)(m0 + row) * 1024 + n0 + ck * 8] = val;
    }
}

// ---------------------------------------------------------------------------
// Flash attention v7: swapped QK^T with fused per-kb exp2, softmax-lite,
// gload_lds K/V staging, XCD-bijective swizzle, 4 blocks/CU. (unchanged)
// ---------------------------------------------------------------------------
__global__ __launch_bounds__(256, 4) void attn_k(
    const u16* __restrict__ Qp, const u16* __restrict__ Kp,
    const u16* __restrict__ Vt, const int* __restrict__ mask,
    u16* __restrict__ O)
{
    __shared__ alignas(16) u16 Ks[2][64][64];
    __shared__ alignas(16) u16 Vs[2][64][64];
    __shared__ alignas(16) u16 Pl[4][16][64];

    const int wg = blockIdx.x;
    const int xc = wg & 7;
    const int rm = wg >> 3;
    const int qx = rm & 15;
    const int bh = (rm >> 4) * 8 + xc;
    const int b = bh >> 4, h = bh & 15;
    const int q0 = qx * 128;
    const int tid = threadIdx.x, wid = tid >> 6, lane = tid & 63;
    const int ql = lane & 15, g = lane >> 4;
    const int qw = q0 + wid * 32;

    const u16* Qbh = Qp + (size_t)bh * 131072;
    const u16* Kbh = Kp + (size_t)bh * 131072;
    const u16* Vbh = Vt + (size_t)bh * 131072;
    const int* mrow = mask + b * 2048;

    char* KsB0 = (char*)Ks;
    char* VsB0 = (char*)Vs;
    char* PlB = (char*)Pl + wid * 2048;

    bf16x8 qf[2][2];
    #pragma unroll
    for (int fi = 0; fi < 2; fi++)
        #pragma unroll
        for (int ks = 0; ks < 2; ks++)
            qf[fi][ks] = *(const bf16x8*)&Qbh[(size_t)(qw + fi * 16 + ql) * 64 + ks * 32 + g * 8];

    f32x4 oacc[2][4] = {};
    float lrow[2] = {0.f, 0.f};
    const f32x4 kZero = {0.f, 0.f, 0.f, 0.f};

    int pwoff[4], proff[2];
    #pragma unroll
    for (int kb = 0; kb < 4; kb++)
        pwoff[kb] = ql * 128 + ((kb * 32 + g * 8) ^ ((ql & 7) << 4));
    #pragma unroll
    for (int ks = 0; ks < 2; ks++)
        proff[ks] = ql * 128 + ((ks * 64 + g * 16) ^ ((ql & 7) << 4));

    const int lrow8 = lane >> 3;
    const int coff  = ((lane & 7) ^ lrow8) << 4;
    const int rb    = wid * 16;

    auto stage = [&](int buf, int tt) {
        const size_t kv0 = (size_t)tt * 64;
        #pragma unroll
        for (int i = 0; i < 2; i++) {
            const int rt = rb + i * 8;
            gload_lds16((const char*)Kbh + (kv0 + rt + lrow8) * 128 + coff,
                        KsB0 + buf * 8192 + rt * 128);
            gload_lds16((const char*)Vbh + (size_t)(rt + lrow8) * 4096 + kv0 * 2 + coff,
                        VsB0 + buf * 8192 + rt * 128);
        }
    };

    stage(0, 0);
    int mcur = mrow[lane];
    __syncthreads();

    for (int t = 0; t < 32; ++t) {
        const int cur = t & 1, nxt = cur ^ 1;
        char* KsB = KsB0 + cur * 8192;
        char* VsB = VsB0 + cur * 8192;
        int mnxt = 1;
        if (t < 31) {
            stage(nxt, t + 1);
            mnxt = mrow[(t + 1) * 64 + lane];
        }
        const bool anym = (__ballot(mcur == 0) != 0ull);

        bf16x8 pf[2][2];
        #pragma unroll
        for (int fi = 0; fi < 2; fi++) {
            float ts = 0.f;
            __builtin_amdgcn_s_setprio(1);
            #pragma unroll
            for (int kb = 0; kb < 4; kb++) {
                const int row = kb * 16 + ql;
                const int swz = (row & 7) << 4;
                bf16x8 kf0 = *(const bf16x8*)(KsB + row * 128 + ((g * 16) ^ swz));
                bf16x8 kf1 = *(const bf16x8*)(KsB + row * 128 + ((64 + g * 16) ^ swz));
                f32x4 a = __builtin_amdgcn_mfma_f32_16x16x32_bf16(kf0, qf[fi][0], kZero, 0, 0, 0);
                a = __builtin_amdgcn_mfma_f32_16x16x32_bf16(kf1, qf[fi][1], a, 0, 0, 0);
                if (anym) {
                    int4 mi = *(const int4*)&mrow[t * 64 + kb * 16 + g * 4];
                    a[0] += mi.x ? 0.f : -1e30f;
                    a[1] += mi.y ? 0.f : -1e30f;
                    a[2] += mi.z ? 0.f : -1e30f;
                    a[3] += mi.w ? 0.f : -1e30f;
                }
                float p0 = EXP2(a[0]);
                float p1 = EXP2(a[1]);
                float p2 = EXP2(a[2]);
                float p3 = EXP2(a[3]);
                ts += (p0 + p1) + (p2 + p3);
                bf16x4 pb;
                pb[0] = (__bf16)p0; pb[1] = (__bf16)p1;
                pb[2] = (__bf16)p2; pb[3] = (__bf16)p3;
                *(bf16x4*)(PlB + pwoff[kb]) = pb;
            }
            __builtin_amdgcn_s_setprio(0);
            lrow[fi] += ts;
            pf[fi][0] = *(const bf16x8*)(PlB + proff[0]);
            pf[fi][1] = *(const bf16x8*)(PlB + proff[1]);
        }

        __builtin_amdgcn_s_setprio(1);
        #pragma unroll
        for (int dt = 0; dt < 4; dt++) {
            int row = dt * 16 + ql;
            int swz = (row & 7) << 4;
            bf16x8 vf0 = *(const bf16x8*)(VsB + row * 128 + ((g * 16) ^ swz));
            bf16x8 vf1 = *(const bf16x8*)(VsB + row * 128 + ((64 + g * 16) ^ swz));
            #pragma unroll
            for (int fi = 0; fi < 2; fi++) {
                oacc[fi][dt] = __builtin_amdgcn_mfma_f32_16x16x32_bf16(vf0, pf[fi][0], oacc[fi][dt], 0, 0, 0);
                oacc[fi][dt] = __builtin_amdgcn_mfma_f32_16x16x32_bf16(vf1, pf[fi][1], oacc[fi][dt], 0, 0, 0);
            }
        }
        __builtin_amdgcn_s_setprio(0);

        mcur = mnxt;
        __syncthreads();
    }

    #pragma unroll
    for (int fi = 0; fi < 2; fi++) {
        lrow[fi] += __shfl_xor(lrow[fi], 16, 64);
        lrow[fi] += __shfl_xor(lrow[fi], 32, 64);
        float inv = 1.f / lrow[fi];
        #pragma unroll
        for (int dt = 0; dt < 4; dt++) {
            bf16x4 ob;
            ob[0] = (__bf16)(oacc[fi][dt][0] * inv);
            ob[1] = (__bf16)(oacc[fi][dt][1] * inv);
            ob[2] = (__bf16)(oacc[fi][dt][2] * inv);
            ob[3] = (__bf16)(oacc[fi][dt][3] * inv);
            *(bf16x4*)(PlB + ql * 128 + ((dt * 32 + g * 8) ^ ((ql & 7) << 4))) = ob;
        }
        int rr = lane >> 2;
        int q = qw + fi * 16 + rr;
        #pragma unroll
        for (int pass = 0; pass < 2; pass++) {
            int cc = (lane & 3) + pass * 4;
            int4 val = *(const int4*)(PlB + rr * 128 + ((cc * 16) ^ ((rr & 7) << 4)));
            *(int4*)&O[((size_t)(b * 2048 + q)) * 1024 + h * 64 + cc * 8] = val;
        }
    }
}

// ---------------------------------------------------------------------------
// LayerNorm over last dim (1024), row per block, bf16 in / f32 out
// ---------------------------------------------------------------------------
__global__ __launch_bounds__(256) void ln_k(
    const u16* __restrict__ X, const float* __restrict__ gamma,
    const float* __restrict__ beta, float* __restrict__ out)
{
    const int row = blockIdx.x, tid = threadIdx.x;
    ushort4 u = ((const ushort4*)(X + (size_t)row * 1024))[tid];
    float v0 = bf2f(u.x), v1 = bf2f(u.y), v2 = bf2f(u.z), v3 = bf2f(u.w);
    float s = (v0 + v1) + (v2 + v3);
    float s2 = (v0 * v0 + v1 * v1) + (v2 * v2 + v3 * v3);
    #pragma unroll
    for (int off = 1; off < 64; off <<= 1) {
        s  += __shfl_xor(s, off, 64);
        s2 += __shfl_xor(s2, off, 64);
    }
    __shared__ float ss[4], ss2[4];
    int wid = tid >> 6;
    if ((tid & 63) == 0) { ss[wid] = s; ss2[wid] = s2; }
    __syncthreads();
    s = ss[0] + ss[1] + ss[2] + ss[3];
    s2 = ss2[0] + ss2[1] + ss2[2] + ss2[3];
    float mean = s * (1.f / 1024.f);
    float var = s2 * (1.f / 1024.f) - mean * mean;
    float rstd = rsqrtf(var + 1e-5f);
    float4 gm = ((const float4*)gamma)[tid];
    float4 be = ((const float4*)beta)[tid];
    float4 o;
    o.x = (v0 - mean) * rstd * gm.x + be.x;
    o.y = (v1 - mean) * rstd * gm.y + be.y;
    o.z = (v2 - mean) * rstd * gm.z + be.z;
    o.w = (v3 - mean) * rstd * gm.w + be.w;
    ((float4*)(out + (size_t)row * 1024))[tid] = o;
}

// ---------------------------------------------------------------------------
extern "C" void kernel_launch(void* const* d_in, const int* in_sizes, int n_in,
                              void* d_out, int out_size, void* d_ws, size_t ws_size,
                              hipStream_t stream)
{
    const float* queries = (const float*)d_in[0];
    const float* keys    = (const float*)d_in[1];
    const float* values  = (const float*)d_in[2];
    const int*   mask    = (const int*)d_in[3];
    const float* Wq = (const float*)d_in[4];
    const float* bq = (const float*)d_in[5];
    const float* Wk = (const float*)d_in[6];
    const float* bk = (const float*)d_in[7];
    const float* Wv = (const float*)d_in[8];
    const float* bv = (const float*)d_in[9];
    const float* Wo = (const float*)d_in[10];
    const float* bo = (const float*)d_in[11];
    const float* gamma = (const float*)d_in[12];
    const float* beta  = (const float*)d_in[13];

    u16* ws = (u16*)d_ws;
    u16* Wt = ws;                       // 4 x 1048576 u16 (8 MB)
    u16* Qp = ws + 4 * 1048576;         // 8388608 u16 each
    u16* Kp = Qp + 8388608;
    u16* Vt = Kp + 8388608;
    u16* O  = Vt + 8388608;
    u16* X  = Qp;                       // alias: Qp dead after attention (bf16 X)

    // Q pre-scale folds 1/sqrt(64) * log2(e) so softmax runs in exp2 domain
    const float qscale = 0.125f * 1.44269504088896f;

    transpose4<<<dim3(32, 32, 4), 256, 0, stream>>>(Wq, Wk, Wv, Wo, Wt);
    gemm_qkv<<<dim3(1536), 512, 0, stream>>>(queries, keys, values, Wt,
                                             bq, bk, bv, Qp, Kp, Vt, qscale);
    attn_k<<<dim3(1024), 256, 0, stream>>>(Qp, Kp, Vt, mask, O);
    gemm_o<<<dim3(512), 512, 0, stream>>>(O, Wt + 3145728, bo, queries, X);
    ln_k<<<8192, 256, 0, stream>>>(X, gamma, beta, (float*)d_out);
}